// Round 8
// baseline (169.073 us; speedup 1.0000x reference)
//
#include <hip/hip_runtime.h>

#define NN 50000
#define NE 600000
#define NR 500
#define DD 128
#define CAP 64   // bucket capacity per node; deg ~ Poisson(12), P(any>64) ~ 1e-25

// 1 cursor per 128B line (r2: cross-XCD per-line atomic serialization fix)
#define CSTRIDE 32

// NOTE (r3): hipLaunchCooperativeKernel is NOT capturable by this harness's
// hipGraph (silent launch failure -> all-zero output). Multi-dispatch only.
// NOTE (r4): __builtin_nontemporal_load needs ext_vector pointers, not float4.
// NOTE (r6): __device__ BSS survives (only d_ws is poisoned); fused restores
// the zero-cursor invariant after reading.
// NOTE (r7): XCD-local sub-buckets (blockIdx&7 heuristic) = null on fill,
// -3us on fused (voff VALU chain). Reverted. fused shown insensitive to
// -14MB traffic AND +2x VALU -> latency-bound or ~2.4TB/s gather ceiling.
// r8 distinguishes: GPB=5 pipelined blocks hide per-group preamble latency.
__device__ int g_cursor[NN * CSTRIDE];   // 6.4 MB BSS, zero-init

// Zero rows: gather batches padded to 8 with a sentinel word pointing at an
// all-zero h_bf row (index NN) / rel_bf row (index NR) -> +0.0, L1-hot.
#define ZW ((unsigned)NN | ((unsigned)NR << 16))

// ---------------------------------------------------------------------------
// Workspace layout (int units):
//   OFF_BKT : NN*CAP packed (src | typ<<16) bucket entries
//   OFF_HB  : h as bf16   ((NN+1)*DD, last row = zeros)
//   OFF_RELB: rel as bf16 ((NR+1)*DD, last row = zeros)
//   OFF_BP  : [W;L] bf16 MFMA B-fragments (32768 bf16)
// ---------------------------------------------------------------------------
#define OFF_BKT  0
#define OFF_HB   (OFF_BKT + NN * CAP)
#define OFF_RELB (OFF_HB + (NN + 1) * DD / 2)
#define OFF_BP   (OFF_RELB + (NR + 1) * DD / 2)

typedef __bf16 bf16x8 __attribute__((ext_vector_type(8)));
typedef float  f32x4  __attribute__((ext_vector_type(4)));
typedef float  f32x4v __attribute__((ext_vector_type(4)));

#define FILL_BLOCKS ((NE + 255) / 256)   // 2344
#define HB_BLOCKS   3125   // 50000*128/8/256
#define RELB_BLOCKS 32     // 8000 conv threads + 32 zero-row threads
#define PB_BLOCKS   128    // 32768 threads
#define PREP_BLOCKS (FILL_BLOCKS + HB_BLOCKS + RELB_BLOCKS + PB_BLOCKS)

// ---------------------------------------------------------------------------
// prep_fill (r6 exactly): bucket scatter via padded BSS cursor atomics,
// 1 edge/thread; h->bf16, rel->bf16 (+ zero rows), [W;L] -> MFMA B frags:
//   n = ntile*16 + (lane&15), k = kstep*32 + (lane>>4)*8 + j
// ---------------------------------------------------------------------------
__global__ __launch_bounds__(256) void prep_fill(
    const float* __restrict__ h, const float* __restrict__ rel,
    const float* __restrict__ W, const float* __restrict__ L,
    __bf16* __restrict__ h_bf, __bf16* __restrict__ rel_bf,
    __bf16* __restrict__ Bp,
    const int* __restrict__ esrc, const int* __restrict__ edst,
    const int* __restrict__ etyp, unsigned* __restrict__ bucket)
{
    int b = blockIdx.x;
    if (b < FILL_BLOCKS) {
        int e = b * 256 + threadIdx.x;
        if (e >= NE) return;
        int s = __builtin_nontemporal_load(esrc + e);
        int d = __builtin_nontemporal_load(edst + e);
        int t = __builtin_nontemporal_load(etyp + e);
        int pos = atomicAdd(&g_cursor[(size_t)d * CSTRIDE], 1);
        if (pos < CAP) bucket[(size_t)d * CAP + pos] = (unsigned)s | ((unsigned)t << 16);
        return;
    }
    b -= FILL_BLOCKS;
    if (b < HB_BLOCKS) {
        int t = b * 256 + threadIdx.x;            // 8 floats per thread
        const f32x4v* src = (const f32x4v*)h + (size_t)t * 2;
        f32x4v v0 = __builtin_nontemporal_load(src);
        f32x4v v1 = __builtin_nontemporal_load(src + 1);
        bf16x8 o;
        o[0]=(__bf16)v0[0]; o[1]=(__bf16)v0[1]; o[2]=(__bf16)v0[2]; o[3]=(__bf16)v0[3];
        o[4]=(__bf16)v1[0]; o[5]=(__bf16)v1[1]; o[6]=(__bf16)v1[2]; o[7]=(__bf16)v1[3];
        *(bf16x8*)(h_bf + (size_t)t * 8) = o;
    } else if (b < HB_BLOCKS + RELB_BLOCKS) {
        int t = (b - HB_BLOCKS) * 256 + threadIdx.x;
        if (t < NR * DD / 8) {
            const f32x4v* src = (const f32x4v*)rel + (size_t)t * 2;
            f32x4v v0 = src[0], v1 = src[1];
            bf16x8 o;
            o[0]=(__bf16)v0[0]; o[1]=(__bf16)v0[1]; o[2]=(__bf16)v0[2]; o[3]=(__bf16)v0[3];
            o[4]=(__bf16)v1[0]; o[5]=(__bf16)v1[1]; o[6]=(__bf16)v1[2]; o[7]=(__bf16)v1[3];
            *(bf16x8*)(rel_bf + (size_t)t * 8) = o;
        } else if (t < NR * DD / 8 + 16) {         // h_bf zero row (index NN)
            int j = t - NR * DD / 8;
            bf16x8 z;
#pragma unroll
            for (int k = 0; k < 8; ++k) z[k] = (__bf16)0.f;
            *(bf16x8*)(h_bf + (size_t)NN * DD + j * 8) = z;
        } else if (t < NR * DD / 8 + 32) {         // rel_bf zero row (index NR)
            int j = t - NR * DD / 8 - 16;
            bf16x8 z;
#pragma unroll
            for (int k = 0; k < 8; ++k) z[k] = (__bf16)0.f;
            *(bf16x8*)(rel_bf + (size_t)NR * DD + j * 8) = z;
        }
    } else {
        int t = (b - HB_BLOCKS - RELB_BLOCKS) * 256 + threadIdx.x;  // [0,32768)
        int lane  = (t >> 3) & 63;
        int ntile = (t >> 9) & 7;
        int kstep = t >> 12;
        int n = ntile * 16 + (lane & 15);
        int k = kstep * 32 + (lane >> 4) * 8 + (t & 7);
        float v = (k < DD) ? W[k * DD + n] : L[(k - DD) * DD + n];
        Bp[t] = (__bf16)v;
    }
}

// ---------------------------------------------------------------------------
// fused_gather_mfma: GPB=5 node-groups per block (grid = 625, exact),
// double-buffered A-tile, ONE barrier per group. Pipeline per group t:
//   write As[p] <- gathered regs(t); barrier;
//   ISSUE group t+1 preamble loads (bucket words / cursor / own row / norm --
//     the 2 serialized latency hops) -- they fly during...
//   MFMA(t) from As[p] + relu + nontemporal store;
//   FINISH gather(t+1): row-load batches start from already-arrived words.
// Hazard-free with 2 buffers + 1 barrier: W(t+2,b) after B(t+1) >= all
// waves' M(t,b) which precede their B(t+1).
// ---------------------------------------------------------------------------
#define AP 264   // bf16 pitch; row = 528 B (16B-aligned for b128)
#define GPB 5
#define FGRID (NN / 16 / GPB)   // 625

__global__ __launch_bounds__(256) void fused_gather_mfma(
    const __bf16* __restrict__ h_bf, const __bf16* __restrict__ rel_bf,
    const float* __restrict__ norm,
    const unsigned* __restrict__ bucket, const __bf16* __restrict__ Bp,
    float* __restrict__ out)
{
    __shared__ __bf16 As[2][16 * AP];   // 16896 B
    int tid  = threadIdx.x;
    int g    = tid >> 4;             // node group 0..15
    int gl   = tid & 15;             // lane within node: bf16 [gl*8, gl*8+8)
    int lane = tid & 63;
    int wave = tid >> 6;
    int aoff = (lane & 15) * AP + (lane >> 4) * 8;
    int nt0  = wave * 2;
    int quad = lane >> 4;
    int col  = lane & 15;
    int grp0 = blockIdx.x * GPB;

    // ---------- prologue: full gather for group grp0 ----------
    bf16x8 o, own_h;
    {
        int node = grp0 * 16 + g;
        const unsigned* bk = bucket + (size_t)node * CAP;
        unsigned w[8];
#pragma unroll
        for (int u = 0; u < 8; ++u) w[u] = bk[u];
        int n = g_cursor[(size_t)node * CSTRIDE];
        if (gl == 0) g_cursor[(size_t)node * CSTRIDE] = 0;   // restore invariant
        own_h = *(const bf16x8*)(h_bf + (size_t)node * DD + gl * 8);
        float sc = norm[node];
        n = (n < CAP) ? n : CAP;
        float acc[8];
#pragma unroll
        for (int j = 0; j < 8; ++j) acc[j] = 0.f;
        int nb = (n + 7) >> 3;
        for (int b = 0; b < nb; ++b) {
            int vbase = b * 8;
            bf16x8 a[8], r[8];
#pragma unroll
            for (int u = 0; u < 8; ++u) {
                unsigned wu = (vbase + u < n) ? w[u] : ZW;   // pad -> zero rows
                a[u] = *(const bf16x8*)(h_bf   + (size_t)(wu & 0xFFFFu) * DD + gl * 8);
                r[u] = *(const bf16x8*)(rel_bf + (size_t)(wu >> 16)     * DD + gl * 8);
            }
#pragma unroll
            for (int u = 0; u < 8; ++u) w[u] = bk[vbase + 8 + u];  // prefetch
#pragma unroll
            for (int u = 0; u < 8; ++u)
#pragma unroll
                for (int j = 0; j < 8; ++j)
                    acc[j] += (float)a[u][j] + (float)r[u][j];
        }
#pragma unroll
        for (int j = 0; j < 8; ++j) o[j] = (__bf16)(acc[j] * sc);
    }

    int p = 0;
    for (int t = 0; t < GPB; ++t) {
        int row0 = (grp0 + t) * 16;
        *(bf16x8*)&As[p][g * AP + gl * 8] = o;
        *(bf16x8*)&As[p][g * AP + DD + gl * 8] = own_h;
        __syncthreads();

        // ---- issue next group's preamble loads (hide under MFMA+store) ----
        unsigned w[8];
        int n = 0;
        const unsigned* bk = nullptr;
        bf16x8 next_own;
        float nsc = 0.f;
        if (t + 1 < GPB) {
            int nnode = row0 + 16 + g;
            bk = bucket + (size_t)nnode * CAP;
#pragma unroll
            for (int u = 0; u < 8; ++u) w[u] = bk[u];
            n = g_cursor[(size_t)nnode * CSTRIDE];
            if (gl == 0) g_cursor[(size_t)nnode * CSTRIDE] = 0;
            next_own = *(const bf16x8*)(h_bf + (size_t)nnode * DD + gl * 8);
            nsc = norm[nnode];
            n = (n < CAP) ? n : CAP;
        }

        // ---- MFMA(t): wave w -> n-tiles 2w,2w+1 over shared 16 A-rows ----
        f32x4 c0 = (f32x4)0.f, c1 = (f32x4)0.f;
#pragma unroll
        for (int kstep = 0; kstep < 8; ++kstep) {
            bf16x8 a = *(const bf16x8*)&As[p][aoff + kstep * 32];
            const __bf16* bbase = Bp + ((size_t)(kstep * 8 + nt0) * 64 + lane) * 8;
            bf16x8 b0 = *(const bf16x8*)bbase;
            bf16x8 b1 = *(const bf16x8*)(bbase + 64 * 8);
            c0 = __builtin_amdgcn_mfma_f32_16x16x32_bf16(a, b0, c0, 0, 0, 0);
            c1 = __builtin_amdgcn_mfma_f32_16x16x32_bf16(a, b1, c1, 0, 0, 0);
        }
        // epilogue: C/D layout col=lane&15, row=(lane>>4)*4+reg
#pragma unroll
        for (int reg = 0; reg < 4; ++reg) {
            float* op = out + (size_t)(row0 + quad * 4 + reg) * DD + col;
            __builtin_nontemporal_store(fmaxf(c0[reg], 0.f), op + nt0 * 16);
            __builtin_nontemporal_store(fmaxf(c1[reg], 0.f), op + (nt0 + 1) * 16);
        }

        // ---- finish gather(t+1): rows start from already-arrived words ----
        if (t + 1 < GPB) {
            float acc[8];
#pragma unroll
            for (int j = 0; j < 8; ++j) acc[j] = 0.f;
            int nb = (n + 7) >> 3;
            for (int b = 0; b < nb; ++b) {
                int vbase = b * 8;
                bf16x8 a[8], r[8];
#pragma unroll
                for (int u = 0; u < 8; ++u) {
                    unsigned wu = (vbase + u < n) ? w[u] : ZW;
                    a[u] = *(const bf16x8*)(h_bf   + (size_t)(wu & 0xFFFFu) * DD + gl * 8);
                    r[u] = *(const bf16x8*)(rel_bf + (size_t)(wu >> 16)     * DD + gl * 8);
                }
#pragma unroll
                for (int u = 0; u < 8; ++u) w[u] = bk[vbase + 8 + u];
#pragma unroll
                for (int u = 0; u < 8; ++u)
#pragma unroll
                    for (int j = 0; j < 8; ++j)
                        acc[j] += (float)a[u][j] + (float)r[u][j];
            }
#pragma unroll
            for (int j = 0; j < 8; ++j) o[j] = (__bf16)(acc[j] * nsc);
            own_h = next_own;
        }
        p ^= 1;
    }
}

extern "C" void kernel_launch(void* const* d_in, const int* in_sizes, int n_in,
                              void* d_out, int out_size, void* d_ws, size_t ws_size,
                              hipStream_t stream) {
    const float* h    = (const float*)d_in[0];
    const float* norm = (const float*)d_in[1];
    const float* rel  = (const float*)d_in[2];
    const float* W    = (const float*)d_in[3];
    const float* L    = (const float*)d_in[4];
    const int* esrc   = (const int*)d_in[5];
    const int* edst   = (const int*)d_in[6];
    const int* etyp   = (const int*)d_in[7];
    float* out = (float*)d_out;

    int* ws = (int*)d_ws;
    unsigned* bucket = (unsigned*)(ws + OFF_BKT);
    __bf16* h_bf     = (__bf16*)(ws + OFF_HB);
    __bf16* rel_bf   = (__bf16*)(ws + OFF_RELB);
    __bf16* Bp       = (__bf16*)(ws + OFF_BP);

    prep_fill<<<PREP_BLOCKS, 256, 0, stream>>>(h, rel, W, L, h_bf, rel_bf, Bp,
                                               esrc, edst, etyp, bucket);
    fused_gather_mfma<<<FGRID, 256, 0, stream>>>(h_bf, rel_bf, norm,
                                                 bucket, Bp, out);
}

// Round 9
// 161.143 us; speedup vs baseline: 1.0492x; 1.0492x over previous
//
#include <hip/hip_runtime.h>

#define NN 50000
#define NE 600000
#define NR 500
#define DD 128
#define CAP 64   // bucket capacity per node; deg ~ Poisson(12), P(any>64) ~ 1e-25

// 1 cursor per 128B line (r2: cross-XCD per-line atomic serialization fix)
#define CSTRIDE 32

// NOTE (r3): hipLaunchCooperativeKernel is NOT capturable by this harness's
// hipGraph (silent launch failure -> all-zero output). Multi-dispatch only.
// NOTE (r4): __builtin_nontemporal_load needs ext_vector pointers, not float4.
// NOTE (r6): __device__ BSS survives (only d_ws is poisoned); fused restores
// the zero-cursor invariant after reading.
// NOTE (r7): XCD-local sub-buckets null on fill, -3us on fused. Reverted.
// NOTE (r8): GPB=5 (grid 625) halved occupancy, fused 46->50.5us. Fused is
// concurrency-bound: waves x in-flight-loads is the product that matters.
// Gather BW saturates sublinearly toward ~2.6-2.8 TB/s.
// r9: deepen gather batch 8->12 edges (+32 VGPR, stays under the 128-VGPR
// occupancy step) -> +50% in-flight h lines per wave at unchanged occupancy.
__device__ int g_cursor[NN * CSTRIDE];   // 6.4 MB BSS, zero-init

// Zero rows: gather batches padded to DEPTH with a sentinel word pointing at
// an all-zero h_bf row (index NN) / rel_bf row (index NR) -> +0.0, L1-hot.
#define ZW ((unsigned)NN | ((unsigned)NR << 16))
#define DEPTH 12

// ---------------------------------------------------------------------------
// Workspace layout (int units):
//   OFF_BKT : NN*CAP packed (src | typ<<16) bucket entries
//   OFF_HB  : h as bf16   ((NN+1)*DD, last row = zeros)
//   OFF_RELB: rel as bf16 ((NR+1)*DD, last row = zeros)
//   OFF_BP  : [W;L] bf16 MFMA B-fragments (32768 bf16)
// ---------------------------------------------------------------------------
#define OFF_BKT  0
#define OFF_HB   (OFF_BKT + NN * CAP)
#define OFF_RELB (OFF_HB + (NN + 1) * DD / 2)
#define OFF_BP   (OFF_RELB + (NR + 1) * DD / 2)

typedef __bf16 bf16x8 __attribute__((ext_vector_type(8)));
typedef float  f32x4  __attribute__((ext_vector_type(4)));
typedef float  f32x4v __attribute__((ext_vector_type(4)));

#define FILL_BLOCKS ((NE + 255) / 256)   // 2344
#define HB_BLOCKS   3125   // 50000*128/8/256
#define RELB_BLOCKS 32     // 8000 conv threads + 32 zero-row threads
#define PB_BLOCKS   128    // 32768 threads
#define PREP_BLOCKS (FILL_BLOCKS + HB_BLOCKS + RELB_BLOCKS + PB_BLOCKS)

// ---------------------------------------------------------------------------
// prep_fill (r6 exactly): bucket scatter via padded BSS cursor atomics,
// 1 edge/thread; h->bf16, rel->bf16 (+ zero rows), [W;L] -> MFMA B frags:
//   n = ntile*16 + (lane&15), k = kstep*32 + (lane>>4)*8 + j
// ---------------------------------------------------------------------------
__global__ __launch_bounds__(256) void prep_fill(
    const float* __restrict__ h, const float* __restrict__ rel,
    const float* __restrict__ W, const float* __restrict__ L,
    __bf16* __restrict__ h_bf, __bf16* __restrict__ rel_bf,
    __bf16* __restrict__ Bp,
    const int* __restrict__ esrc, const int* __restrict__ edst,
    const int* __restrict__ etyp, unsigned* __restrict__ bucket)
{
    int b = blockIdx.x;
    if (b < FILL_BLOCKS) {
        int e = b * 256 + threadIdx.x;
        if (e >= NE) return;
        int s = __builtin_nontemporal_load(esrc + e);
        int d = __builtin_nontemporal_load(edst + e);
        int t = __builtin_nontemporal_load(etyp + e);
        int pos = atomicAdd(&g_cursor[(size_t)d * CSTRIDE], 1);
        if (pos < CAP) bucket[(size_t)d * CAP + pos] = (unsigned)s | ((unsigned)t << 16);
        return;
    }
    b -= FILL_BLOCKS;
    if (b < HB_BLOCKS) {
        int t = b * 256 + threadIdx.x;            // 8 floats per thread
        const f32x4v* src = (const f32x4v*)h + (size_t)t * 2;
        f32x4v v0 = __builtin_nontemporal_load(src);
        f32x4v v1 = __builtin_nontemporal_load(src + 1);
        bf16x8 o;
        o[0]=(__bf16)v0[0]; o[1]=(__bf16)v0[1]; o[2]=(__bf16)v0[2]; o[3]=(__bf16)v0[3];
        o[4]=(__bf16)v1[0]; o[5]=(__bf16)v1[1]; o[6]=(__bf16)v1[2]; o[7]=(__bf16)v1[3];
        *(bf16x8*)(h_bf + (size_t)t * 8) = o;
    } else if (b < HB_BLOCKS + RELB_BLOCKS) {
        int t = (b - HB_BLOCKS) * 256 + threadIdx.x;
        if (t < NR * DD / 8) {
            const f32x4v* src = (const f32x4v*)rel + (size_t)t * 2;
            f32x4v v0 = src[0], v1 = src[1];
            bf16x8 o;
            o[0]=(__bf16)v0[0]; o[1]=(__bf16)v0[1]; o[2]=(__bf16)v0[2]; o[3]=(__bf16)v0[3];
            o[4]=(__bf16)v1[0]; o[5]=(__bf16)v1[1]; o[6]=(__bf16)v1[2]; o[7]=(__bf16)v1[3];
            *(bf16x8*)(rel_bf + (size_t)t * 8) = o;
        } else if (t < NR * DD / 8 + 16) {         // h_bf zero row (index NN)
            int j = t - NR * DD / 8;
            bf16x8 z;
#pragma unroll
            for (int k = 0; k < 8; ++k) z[k] = (__bf16)0.f;
            *(bf16x8*)(h_bf + (size_t)NN * DD + j * 8) = z;
        } else if (t < NR * DD / 8 + 32) {         // rel_bf zero row (index NR)
            int j = t - NR * DD / 8 - 16;
            bf16x8 z;
#pragma unroll
            for (int k = 0; k < 8; ++k) z[k] = (__bf16)0.f;
            *(bf16x8*)(rel_bf + (size_t)NR * DD + j * 8) = z;
        }
    } else {
        int t = (b - HB_BLOCKS - RELB_BLOCKS) * 256 + threadIdx.x;  // [0,32768)
        int lane  = (t >> 3) & 63;
        int ntile = (t >> 9) & 7;
        int kstep = t >> 12;
        int n = ntile * 16 + (lane & 15);
        int k = kstep * 32 + (lane >> 4) * 8 + (t & 7);
        float v = (k < DD) ? W[k * DD + n] : L[(k - DD) * DD + n];
        Bp[t] = (__bf16)v;
    }
}

// ---------------------------------------------------------------------------
// fused_gather_mfma: 16 nodes per block (grid = NN/16 = 3125, exact).
//   phase 1: gather. DEPTH=12 edge batches (24 row loads in flight/lane,
//     +50% MLP vs r6's 8 at ~100 VGPR -- under the 128 occupancy step):
//     - bk[0..DEPTH) loaded unconditionally before the cursor value arrives
//     - uniform masked batches, invalid slots -> zero rows (no serial tail)
//     - next batch's words prefetched (OOB offsets stay inside ws; discarded)
//     - cursor reset to 0 after read (restores invariant)
//   phase 2: all 4 waves share the 16 A-rows; wave w computes n-tiles
//            {2w, 2w+1}: 8 ksteps x 2 = 16 MFMA/wave. relu, nontemporal store.
// ---------------------------------------------------------------------------
#define AP 264   // bf16 pitch; row = 528 B (16B-aligned for b128)

__global__ __launch_bounds__(256) void fused_gather_mfma(
    const __bf16* __restrict__ h_bf, const __bf16* __restrict__ rel_bf,
    const float* __restrict__ norm,
    const unsigned* __restrict__ bucket, const __bf16* __restrict__ Bp,
    float* __restrict__ out)
{
    __shared__ __bf16 As[16 * AP];   // 8448 B
    int tid = threadIdx.x;
    int row0 = blockIdx.x * 16;
    int g    = tid >> 4;             // node group 0..15
    int gl   = tid & 15;             // lane within node: bf16 [gl*8, gl*8+8)
    int node = row0 + g;             // always < NN (exact grid)

    // earliest possible: bucket words (independent of cursor value)
    const unsigned* bk = bucket + (size_t)node * CAP;
    unsigned w[DEPTH];
#pragma unroll
    for (int u = 0; u < DEPTH; ++u) w[u] = bk[u];

    int n = g_cursor[(size_t)node * CSTRIDE];
    if (gl == 0) g_cursor[(size_t)node * CSTRIDE] = 0;   // restore invariant
    bf16x8 own_h = *(const bf16x8*)(h_bf + (size_t)node * DD + gl * 8);
    float sc = norm[node];
    n = (n < CAP) ? n : CAP;

    float acc[8];
#pragma unroll
    for (int j = 0; j < 8; ++j) acc[j] = 0.f;

    int nb = (n + DEPTH - 1) / DEPTH;
    for (int b = 0; b < nb; ++b) {
        int vbase = b * DEPTH;
        bf16x8 a[DEPTH], r[DEPTH];
#pragma unroll
        for (int u = 0; u < DEPTH; ++u) {
            unsigned wu = (vbase + u < n) ? w[u] : ZW;   // pad -> zero rows
            a[u] = *(const bf16x8*)(h_bf   + (size_t)(wu & 0xFFFFu) * DD + gl * 8);
            r[u] = *(const bf16x8*)(rel_bf + (size_t)(wu >> 16)     * DD + gl * 8);
        }
#pragma unroll
        for (int u = 0; u < DEPTH; ++u) w[u] = bk[vbase + DEPTH + u];  // prefetch
#pragma unroll
        for (int u = 0; u < DEPTH; ++u)
#pragma unroll
            for (int j = 0; j < 8; ++j)
                acc[j] += (float)a[u][j] + (float)r[u][j];
    }

    bf16x8 o;
#pragma unroll
    for (int j = 0; j < 8; ++j) o[j] = (__bf16)(acc[j] * sc);
    *(bf16x8*)&As[g * AP + gl * 8] = o;
    *(bf16x8*)&As[g * AP + DD + gl * 8] = own_h;
    __syncthreads();

    // ---- phase 2: MFMA. wave w -> n-tiles 2w, 2w+1 over shared 16 A-rows.
    int lane = tid & 63;
    int wave = tid >> 6;
    int aoff = (lane & 15) * AP + (lane >> 4) * 8;

    f32x4 c0 = (f32x4)0.f, c1 = (f32x4)0.f;
    int nt0 = wave * 2;
#pragma unroll
    for (int kstep = 0; kstep < 8; ++kstep) {
        bf16x8 a = *(const bf16x8*)&As[aoff + kstep * 32];
        const __bf16* bbase = Bp + ((size_t)(kstep * 8 + nt0) * 64 + lane) * 8;
        bf16x8 b0 = *(const bf16x8*)bbase;
        bf16x8 b1 = *(const bf16x8*)(bbase + 64 * 8);
        c0 = __builtin_amdgcn_mfma_f32_16x16x32_bf16(a, b0, c0, 0, 0, 0);
        c1 = __builtin_amdgcn_mfma_f32_16x16x32_bf16(a, b1, c1, 0, 0, 0);
    }

    // epilogue: C/D layout col=lane&15, row=(lane>>4)*4+reg; rows all < NN.
    // nontemporal: out is a 25.6MB single-use stream; don't evict h_bf from L2
    int quad = lane >> 4;
    int col  = lane & 15;
#pragma unroll
    for (int reg = 0; reg < 4; ++reg) {
        float* op = out + (size_t)(row0 + quad * 4 + reg) * DD + col;
        __builtin_nontemporal_store(fmaxf(c0[reg], 0.f), op + nt0 * 16);
        __builtin_nontemporal_store(fmaxf(c1[reg], 0.f), op + (nt0 + 1) * 16);
    }
}

extern "C" void kernel_launch(void* const* d_in, const int* in_sizes, int n_in,
                              void* d_out, int out_size, void* d_ws, size_t ws_size,
                              hipStream_t stream) {
    const float* h    = (const float*)d_in[0];
    const float* norm = (const float*)d_in[1];
    const float* rel  = (const float*)d_in[2];
    const float* W    = (const float*)d_in[3];
    const float* L    = (const float*)d_in[4];
    const int* esrc   = (const int*)d_in[5];
    const int* edst   = (const int*)d_in[6];
    const int* etyp   = (const int*)d_in[7];
    float* out = (float*)d_out;

    int* ws = (int*)d_ws;
    unsigned* bucket = (unsigned*)(ws + OFF_BKT);
    __bf16* h_bf     = (__bf16*)(ws + OFF_HB);
    __bf16* rel_bf   = (__bf16*)(ws + OFF_RELB);
    __bf16* Bp       = (__bf16*)(ws + OFF_BP);

    prep_fill<<<PREP_BLOCKS, 256, 0, stream>>>(h, rel, W, L, h_bf, rel_bf, Bp,
                                               esrc, edst, etyp, bucket);
    fused_gather_mfma<<<NN / 16, 256, 0, stream>>>(h_bf, rel_bf, norm,
                                                   bucket, Bp, out);
}

// Round 10
// 157.954 us; speedup vs baseline: 1.0704x; 1.0202x over previous
//
#include <hip/hip_runtime.h>

#define NN 50000
#define NE 600000
#define NR 500
#define DD 128
#define CAP 64   // bucket capacity per node; deg ~ Poisson(12), P(any>64) ~ 1e-25

// 1 cursor per 128B line (r2: cross-XCD per-line atomic serialization fix)
#define CSTRIDE 32

// NOTE (r3): hipLaunchCooperativeKernel is NOT capturable by this harness's
// hipGraph (silent launch failure -> all-zero output). Multi-dispatch only.
// NOTE (r4): __builtin_nontemporal_load needs ext_vector pointers, not float4.
// NOTE (r6): __device__ BSS survives (only d_ws is poisoned); fused restores
// the zero-cursor invariant after reading.
// NOTE (r7): XCD-local sub-buckets null on fill, -3us on fused. Reverted.
// NOTE (r8): GPB=5 (grid 625) halved occupancy, fused 46->50.5us: fused is
// concurrency-bound; per-wave pipelining cannot replace wave parallelism.
// NOTE (r9): DEPTH=12 (+50% in-flight/wave) null -> 8-deep at full occupancy
// already saturates the ~2.5-2.6 TB/s random 256B-gather throughput knee.
// FINAL (r10): revert to the r6 best-measured structure (157.3us). Ceiling
// accounting: poison fill ~44 (harness-fixed) + out-zero ~4 + resets/gaps
// ~10-15 + prep_fill ~40 (600k returning-atomic floor, conversion overlapped)
// + fused ~44 (random-gather throughput floor on ~110MB) ~= 155-165us.
__device__ int g_cursor[NN * CSTRIDE];   // 6.4 MB BSS, zero-init

// Zero rows: gather batches padded to 8 with a sentinel word pointing at an
// all-zero h_bf row (index NN) / rel_bf row (index NR) -> +0.0, L1-hot.
#define ZW ((unsigned)NN | ((unsigned)NR << 16))

// ---------------------------------------------------------------------------
// Workspace layout (int units):
//   OFF_BKT : NN*CAP packed (src | typ<<16) bucket entries
//   OFF_HB  : h as bf16   ((NN+1)*DD, last row = zeros)
//   OFF_RELB: rel as bf16 ((NR+1)*DD, last row = zeros)
//   OFF_BP  : [W;L] bf16 MFMA B-fragments (32768 bf16)
// ---------------------------------------------------------------------------
#define OFF_BKT  0
#define OFF_HB   (OFF_BKT + NN * CAP)
#define OFF_RELB (OFF_HB + (NN + 1) * DD / 2)
#define OFF_BP   (OFF_RELB + (NR + 1) * DD / 2)

typedef __bf16 bf16x8 __attribute__((ext_vector_type(8)));
typedef float  f32x4  __attribute__((ext_vector_type(4)));
typedef float  f32x4v __attribute__((ext_vector_type(4)));

#define FILL_BLOCKS ((NE + 255) / 256)   // 2344
#define HB_BLOCKS   3125   // 50000*128/8/256
#define RELB_BLOCKS 32     // 8000 conv threads + 32 zero-row threads
#define PB_BLOCKS   128    // 32768 threads
#define PREP_BLOCKS (FILL_BLOCKS + HB_BLOCKS + RELB_BLOCKS + PB_BLOCKS)

// ---------------------------------------------------------------------------
// prep_fill: bucket scatter via padded BSS cursor atomics, 1 edge/thread;
// h->bf16, rel->bf16 (+ zero rows), [W;L] -> MFMA B frags:
//   n = ntile*16 + (lane&15), k = kstep*32 + (lane>>4)*8 + j
// ---------------------------------------------------------------------------
__global__ __launch_bounds__(256) void prep_fill(
    const float* __restrict__ h, const float* __restrict__ rel,
    const float* __restrict__ W, const float* __restrict__ L,
    __bf16* __restrict__ h_bf, __bf16* __restrict__ rel_bf,
    __bf16* __restrict__ Bp,
    const int* __restrict__ esrc, const int* __restrict__ edst,
    const int* __restrict__ etyp, unsigned* __restrict__ bucket)
{
    int b = blockIdx.x;
    if (b < FILL_BLOCKS) {
        int e = b * 256 + threadIdx.x;
        if (e >= NE) return;
        int s = __builtin_nontemporal_load(esrc + e);
        int d = __builtin_nontemporal_load(edst + e);
        int t = __builtin_nontemporal_load(etyp + e);
        int pos = atomicAdd(&g_cursor[(size_t)d * CSTRIDE], 1);
        if (pos < CAP) bucket[(size_t)d * CAP + pos] = (unsigned)s | ((unsigned)t << 16);
        return;
    }
    b -= FILL_BLOCKS;
    if (b < HB_BLOCKS) {
        int t = b * 256 + threadIdx.x;            // 8 floats per thread
        const f32x4v* src = (const f32x4v*)h + (size_t)t * 2;
        f32x4v v0 = __builtin_nontemporal_load(src);
        f32x4v v1 = __builtin_nontemporal_load(src + 1);
        bf16x8 o;
        o[0]=(__bf16)v0[0]; o[1]=(__bf16)v0[1]; o[2]=(__bf16)v0[2]; o[3]=(__bf16)v0[3];
        o[4]=(__bf16)v1[0]; o[5]=(__bf16)v1[1]; o[6]=(__bf16)v1[2]; o[7]=(__bf16)v1[3];
        *(bf16x8*)(h_bf + (size_t)t * 8) = o;
    } else if (b < HB_BLOCKS + RELB_BLOCKS) {
        int t = (b - HB_BLOCKS) * 256 + threadIdx.x;
        if (t < NR * DD / 8) {
            const f32x4v* src = (const f32x4v*)rel + (size_t)t * 2;
            f32x4v v0 = src[0], v1 = src[1];
            bf16x8 o;
            o[0]=(__bf16)v0[0]; o[1]=(__bf16)v0[1]; o[2]=(__bf16)v0[2]; o[3]=(__bf16)v0[3];
            o[4]=(__bf16)v1[0]; o[5]=(__bf16)v1[1]; o[6]=(__bf16)v1[2]; o[7]=(__bf16)v1[3];
            *(bf16x8*)(rel_bf + (size_t)t * 8) = o;
        } else if (t < NR * DD / 8 + 16) {         // h_bf zero row (index NN)
            int j = t - NR * DD / 8;
            bf16x8 z;
#pragma unroll
            for (int k = 0; k < 8; ++k) z[k] = (__bf16)0.f;
            *(bf16x8*)(h_bf + (size_t)NN * DD + j * 8) = z;
        } else if (t < NR * DD / 8 + 32) {         // rel_bf zero row (index NR)
            int j = t - NR * DD / 8 - 16;
            bf16x8 z;
#pragma unroll
            for (int k = 0; k < 8; ++k) z[k] = (__bf16)0.f;
            *(bf16x8*)(rel_bf + (size_t)NR * DD + j * 8) = z;
        }
    } else {
        int t = (b - HB_BLOCKS - RELB_BLOCKS) * 256 + threadIdx.x;  // [0,32768)
        int lane  = (t >> 3) & 63;
        int ntile = (t >> 9) & 7;
        int kstep = t >> 12;
        int n = ntile * 16 + (lane & 15);
        int k = kstep * 32 + (lane >> 4) * 8 + (t & 7);
        float v = (k < DD) ? W[k * DD + n] : L[(k - DD) * DD + n];
        Bp[t] = (__bf16)v;
    }
}

// ---------------------------------------------------------------------------
// fused_gather_mfma: 16 nodes per block (grid = NN/16 = 3125, exact).
//   phase 1: gather. Per-node critical chain minimized:
//     - bk[0..8) loaded UNCONDITIONALLY before the cursor value arrives
//     - ONE uniform batch loop, nb=ceil(n/8): invalid slots redirected to the
//       zero rows (contribute +0.0, L1-hot) -- no serial tail
//     - next batch's words prefetched during current batch (OOB reads land in
//       adjacent ws regions: in-bounds garbage, discarded)
//     - cursor reset to 0 after read (restores fill invariant)
//   phase 2: all 4 waves share the 16 A-rows; wave w computes n-tiles
//            {2w, 2w+1}: 8 ksteps x 2 = 16 MFMA/wave. relu, nontemporal store.
// ---------------------------------------------------------------------------
#define AP 264   // bf16 pitch; row = 528 B (16B-aligned for b128)

__global__ __launch_bounds__(256) void fused_gather_mfma(
    const __bf16* __restrict__ h_bf, const __bf16* __restrict__ rel_bf,
    const float* __restrict__ norm,
    const unsigned* __restrict__ bucket, const __bf16* __restrict__ Bp,
    float* __restrict__ out)
{
    __shared__ __bf16 As[16 * AP];   // 8448 B
    int tid = threadIdx.x;
    int row0 = blockIdx.x * 16;
    int g    = tid >> 4;             // node group 0..15
    int gl   = tid & 15;             // lane within node: bf16 [gl*8, gl*8+8)
    int node = row0 + g;             // always < NN (exact grid)

    // earliest possible: bucket words (independent of cursor value)
    const unsigned* bk = bucket + (size_t)node * CAP;
    unsigned w[8];
#pragma unroll
    for (int u = 0; u < 8; ++u) w[u] = bk[u];

    int n = g_cursor[(size_t)node * CSTRIDE];
    if (gl == 0) g_cursor[(size_t)node * CSTRIDE] = 0;   // restore invariant
    bf16x8 own_h = *(const bf16x8*)(h_bf + (size_t)node * DD + gl * 8);
    float sc = norm[node];
    n = (n < CAP) ? n : CAP;

    float acc[8];
#pragma unroll
    for (int j = 0; j < 8; ++j) acc[j] = 0.f;

    int nb = (n + 7) >> 3;
    for (int b = 0; b < nb; ++b) {
        int vbase = b * 8;
        bf16x8 a[8], r[8];
#pragma unroll
        for (int u = 0; u < 8; ++u) {
            unsigned wu = (vbase + u < n) ? w[u] : ZW;   // pad -> zero rows
            a[u] = *(const bf16x8*)(h_bf   + (size_t)(wu & 0xFFFFu) * DD + gl * 8);
            r[u] = *(const bf16x8*)(rel_bf + (size_t)(wu >> 16)     * DD + gl * 8);
        }
#pragma unroll
        for (int u = 0; u < 8; ++u) w[u] = bk[vbase + 8 + u];  // prefetch
#pragma unroll
        for (int u = 0; u < 8; ++u)
#pragma unroll
            for (int j = 0; j < 8; ++j)
                acc[j] += (float)a[u][j] + (float)r[u][j];
    }

    bf16x8 o;
#pragma unroll
    for (int j = 0; j < 8; ++j) o[j] = (__bf16)(acc[j] * sc);
    *(bf16x8*)&As[g * AP + gl * 8] = o;
    *(bf16x8*)&As[g * AP + DD + gl * 8] = own_h;
    __syncthreads();

    // ---- phase 2: MFMA. wave w -> n-tiles 2w, 2w+1 over shared 16 A-rows.
    int lane = tid & 63;
    int wave = tid >> 6;
    int aoff = (lane & 15) * AP + (lane >> 4) * 8;

    f32x4 c0 = (f32x4)0.f, c1 = (f32x4)0.f;
    int nt0 = wave * 2;
#pragma unroll
    for (int kstep = 0; kstep < 8; ++kstep) {
        bf16x8 a = *(const bf16x8*)&As[aoff + kstep * 32];
        const __bf16* bbase = Bp + ((size_t)(kstep * 8 + nt0) * 64 + lane) * 8;
        bf16x8 b0 = *(const bf16x8*)bbase;
        bf16x8 b1 = *(const bf16x8*)(bbase + 64 * 8);
        c0 = __builtin_amdgcn_mfma_f32_16x16x32_bf16(a, b0, c0, 0, 0, 0);
        c1 = __builtin_amdgcn_mfma_f32_16x16x32_bf16(a, b1, c1, 0, 0, 0);
    }

    // epilogue: C/D layout col=lane&15, row=(lane>>4)*4+reg; rows all < NN.
    // nontemporal: out is a 25.6MB single-use stream; don't evict h_bf from L2
    int quad = lane >> 4;
    int col  = lane & 15;
#pragma unroll
    for (int reg = 0; reg < 4; ++reg) {
        float* op = out + (size_t)(row0 + quad * 4 + reg) * DD + col;
        __builtin_nontemporal_store(fmaxf(c0[reg], 0.f), op + nt0 * 16);
        __builtin_nontemporal_store(fmaxf(c1[reg], 0.f), op + (nt0 + 1) * 16);
    }
}

extern "C" void kernel_launch(void* const* d_in, const int* in_sizes, int n_in,
                              void* d_out, int out_size, void* d_ws, size_t ws_size,
                              hipStream_t stream) {
    const float* h    = (const float*)d_in[0];
    const float* norm = (const float*)d_in[1];
    const float* rel  = (const float*)d_in[2];
    const float* W    = (const float*)d_in[3];
    const float* L    = (const float*)d_in[4];
    const int* esrc   = (const int*)d_in[5];
    const int* edst   = (const int*)d_in[6];
    const int* etyp   = (const int*)d_in[7];
    float* out = (float*)d_out;

    int* ws = (int*)d_ws;
    unsigned* bucket = (unsigned*)(ws + OFF_BKT);
    __bf16* h_bf     = (__bf16*)(ws + OFF_HB);
    __bf16* rel_bf   = (__bf16*)(ws + OFF_RELB);
    __bf16* Bp       = (__bf16*)(ws + OFF_BP);

    prep_fill<<<PREP_BLOCKS, 256, 0, stream>>>(h, rel, W, L, h_bf, rel_bf, Bp,
                                               esrc, edst, etyp, bucket);
    fused_gather_mfma<<<NN / 16, 256, 0, stream>>>(h_bf, rel_bf, norm,
                                                   bucket, Bp, out);
}